// Round 3
// baseline (466.929 us; speedup 1.0000x reference)
//
#include <hip/hip_runtime.h>
#include <math.h>

#define C 28   // channels == dim_head == rank
#define N 64   // tokens per window (8x8)

// ws layout per problem (floats)
#define QOFF   0
#define KOFF   1792
#define VOFF   3584
#define SGKOFF 5376
#define SQOFF  5440
#define PS     5504   // per-problem stride (floats); *4B = 22016 (16B-aligned)
#define NPROB  8192

// ---------------- kernel 1: projections -> workspace ----------------
__global__ __launch_bounds__(256, 4)
void proj_kernel(const float* __restrict__ x,
                 const float* __restrict__ Wqk,   // [56][28]
                 const float* __restrict__ Wv,    // [28][28]
                 const float* __restrict__ Wpcq,  // [28]
                 const float* __restrict__ bpcq,  // [1]
                 const float* __restrict__ Wpck,  // [28]
                 const float* __restrict__ bpck,  // [1]
                 float* __restrict__ ws)
{
    const int tid = blockIdx.x * 256 + threadIdx.x;
    const int pid = tid >> 6;
    const int ln  = tid & 63;
    const int win = pid >> 3;
    const int Bi  = pid & 7;
    const int hw = win >> 5, ww = win & 31;
    const int b0 = ln >> 3, b1 = ln & 7;
    const size_t base = ((((size_t)Bi * 256) + (size_t)(hw * 8 + b0)) * 256
                         + (size_t)(ww * 8 + b1)) * C;

    float xr[C];
    {
        const float4* p = (const float4*)(x + base);
        #pragma unroll
        for (int i = 0; i < 7; ++i) {
            float4 t = p[i];
            xr[4*i+0] = t.x; xr[4*i+1] = t.y; xr[4*i+2] = t.z; xr[4*i+3] = t.w;
        }
    }

    float* P  = ws + (size_t)pid * PS;
    float* Qr = P + QOFF + ln * C;
    float* Kr = P + KOFF + ln * C;
    float* Vr = P + VOFF + ln * C;

    // ---- q projection + sig_q (chains match R1: a0 even-c / a1 odd-c; sq 2-chain over d) ----
    float sqa0 = 0.f, sqa1 = 0.f;
    #pragma unroll
    for (int d4 = 0; d4 < 7; ++d4) {
        float qq[4];
        #pragma unroll
        for (int t = 0; t < 4; ++t) {
            const int d = 4*d4 + t;
            float a0 = 0.f, a1 = 0.f;
            #pragma unroll
            for (int c = 0; c < C; c += 2) {
                a0 += Wqk[d*C + c]     * xr[c];
                a1 += Wqk[d*C + c + 1] * xr[c+1];
            }
            qq[t] = a0 + a1;
        }
        sqa0 += qq[0] * Wpcq[4*d4+0];
        sqa1 += qq[1] * Wpcq[4*d4+1];
        sqa0 += qq[2] * Wpcq[4*d4+2];
        sqa1 += qq[3] * Wpcq[4*d4+3];
        ((float4*)Qr)[d4] = make_float4(qq[0], qq[1], qq[2], qq[3]);
    }
    P[SQOFF + ln] = sqa0 + sqa1 + bpcq[0];

    // ---- k, v projections + sig_k (single ascending chain, matches R1) ----
    float ak_sig = 0.f;
    #pragma unroll
    for (int d4 = 0; d4 < 7; ++d4) {
        float kk[4], vv[4];
        #pragma unroll
        for (int t = 0; t < 4; ++t) {
            const int d = 4*d4 + t;
            float k0 = 0.f, k1 = 0.f, v0 = 0.f, v1 = 0.f;
            #pragma unroll
            for (int c = 0; c < C; c += 2) {
                k0 += Wqk[(C+d)*C + c]     * xr[c];
                k1 += Wqk[(C+d)*C + c + 1] * xr[c+1];
                v0 += Wv[d*C + c]          * xr[c];
                v1 += Wv[d*C + c + 1]      * xr[c+1];
            }
            kk[t] = k0 + k1;
            vv[t] = v0 + v1;
        }
        ak_sig += kk[0] * Wpck[4*d4+0];
        ak_sig += kk[1] * Wpck[4*d4+1];
        ak_sig += kk[2] * Wpck[4*d4+2];
        ak_sig += kk[3] * Wpck[4*d4+3];
        ((float4*)Kr)[d4] = make_float4(kk[0], kk[1], kk[2], kk[3]);
        ((float4*)Vr)[d4] = make_float4(vv[0], vv[1], vv[2], vv[3]);
    }
    P[SGKOFF + ln] = ak_sig + bpck[0];
}

// ---------------- kernel 2: attention via scalar (SGPR) K/V loads ----------------
__global__ __launch_bounds__(64, 4)
void attn_kernel(const float* __restrict__ ws,
                 const float* __restrict__ Wout,  // [28][28]
                 const float* __restrict__ bout,  // [28]
                 const float* __restrict__ Wm1,   // [64]
                 const float* __restrict__ Wm2a,  // [64][64]
                 const float* __restrict__ Wm2b,  // [64]
                 float* __restrict__ out)
{
    __shared__ float thb[N];

    const int ln  = threadIdx.x;   // 0..63
    const int pid = blockIdx.x;    // wave-uniform: enables s_load for K/V/sgk
    const int win = pid >> 3;
    const int Bi  = pid & 7;
    const int hw = win >> 5, ww = win & 31;
    const int b0 = ln >> 3, b1 = ln & 7;
    const size_t base = ((((size_t)Bi * 256) + (size_t)(hw * 8 + b0)) * 256
                         + (size_t)(ww * 8 + b1)) * C;

    const float* P = ws + (size_t)pid * PS;

    // ---- per-lane q row + sq (vector loads) ----
    float q[C];
    {
        const float4* p = (const float4*)(P + QOFF + ln * C);
        #pragma unroll
        for (int i = 0; i < 7; ++i) {
            float4 t = p[i];
            q[4*i+0] = t.x; q[4*i+1] = t.y; q[4*i+2] = t.z; q[4*i+3] = t.w;
        }
    }
    const float sq = P[SQOFF + ln];

    // ---- pass 1: raw sim -> theta accumulation + row max (K via s_load) ----
    float th = 0.f;
    float m = -1e30f;
    #pragma unroll 2
    for (int j = 0; j < N; ++j) {
        const float* kr = P + KOFF + j * C;       // wave-uniform -> SGPRs
        float a0 = 0.f, a1 = 0.f, a2 = 0.f, a3 = 0.f;
        #pragma unroll
        for (int c4 = 0; c4 < 7; ++c4) {
            a0 += q[4*c4+0] * kr[4*c4+0];
            a1 += q[4*c4+1] * kr[4*c4+1];
            a2 += q[4*c4+2] * kr[4*c4+2];
            a3 += q[4*c4+3] * kr[4*c4+3];
        }
        float sraw = (a0 + a1) + (a2 + a3);
        th += (j == ln) ? 0.f : sraw * Wm1[j];
        float ss = sraw * sq * P[SGKOFF + j];
        m = fmaxf(m, ss);
    }
    thb[ln] = th;
    __syncthreads();

    // ---- MLP2 (matches R1) ----
    float tP;
    {
        const float* thw = &thb[0];
        const float* wrow = Wm2a + ln * N;
        float a0 = 0.f, a1 = 0.f, a2 = 0.f, a3 = 0.f;
        #pragma unroll 4
        for (int i = 0; i < N; i += 4) {
            a0 += thw[i]   * wrow[i];
            a1 += thw[i+1] * wrow[i+1];
            a2 += thw[i+2] * wrow[i+2];
            a3 += thw[i+3] * wrow[i+3];
        }
        float t = (a0 + a1) + (a2 + a3);
        t = (t >= 0.f) ? t : 0.1f * t;
        tP = t * Wm2b[ln];
    }
    float theta = tP;
    #pragma unroll
    for (int off = 32; off > 0; off >>= 1)
        theta += __shfl_xor(theta, off, 64);

    // ---- pass 2: recompute sim (bit-identical chains), softmax+mask+A.V (K,V via s_load) ----
    float o[C];
    #pragma unroll
    for (int d = 0; d < C; ++d) o[d] = 0.f;
    float Z = 0.f;
    #pragma unroll 2
    for (int j = 0; j < N; ++j) {
        const float* kr = P + KOFF + j * C;
        float a0 = 0.f, a1 = 0.f, a2 = 0.f, a3 = 0.f;
        #pragma unroll
        for (int c4 = 0; c4 < 7; ++c4) {
            a0 += q[4*c4+0] * kr[4*c4+0];
            a1 += q[4*c4+1] * kr[4*c4+1];
            a2 += q[4*c4+2] * kr[4*c4+2];
            a3 += q[4*c4+3] * kr[4*c4+3];
        }
        float sraw = (a0 + a1) + (a2 + a3);
        float ss = sraw * sq * P[SGKOFF + j];
        float e = __expf(ss - m);
        Z += e;
        float a = (ss > theta) ? e : 0.f;
        const float* vr = P + VOFF + j * C;       // wave-uniform -> SGPRs
        #pragma unroll
        for (int c4 = 0; c4 < 7; ++c4) {
            o[4*c4+0] += a * vr[4*c4+0];
            o[4*c4+1] += a * vr[4*c4+1];
            o[4*c4+2] += a * vr[4*c4+2];
            o[4*c4+3] += a * vr[4*c4+3];
        }
    }
    {
        float rz = 1.0f / Z;
        #pragma unroll
        for (int d = 0; d < C; ++d) o[d] *= rz;
    }

    // ---- output projection + bias + float4 stores (matches R2 epilogue) ----
    float y[C];
    #pragma unroll
    for (int e = 0; e < C; ++e) {
        float a0 = 0.f, a1 = 0.f;
        #pragma unroll
        for (int d = 0; d < C; d += 2) {
            a0 += Wout[e*C + d]     * o[d];
            a1 += Wout[e*C + d + 1] * o[d+1];
        }
        y[e] = (a0 + a1) + bout[e];
    }
    {
        float4* yp = (float4*)(out + base);
        #pragma unroll
        for (int i = 0; i < 7; ++i)
            yp[i] = make_float4(y[4*i+0], y[4*i+1], y[4*i+2], y[4*i+3]);
    }
}

// ---------------- fallback: proven single-kernel R1 version ----------------
__global__ __launch_bounds__(256, 2)
void fa_fused_fb(const float* __restrict__ x,
                 const float* __restrict__ Wqk, const float* __restrict__ Wv,
                 const float* __restrict__ Wout, const float* __restrict__ bout,
                 const float* __restrict__ Wpcq, const float* __restrict__ bpcq,
                 const float* __restrict__ Wpck, const float* __restrict__ bpck,
                 const float* __restrict__ Wm1, const float* __restrict__ Wm2a,
                 const float* __restrict__ Wm2b, float* __restrict__ out)
{
    __shared__ float kbuf[4][N][C];
    __shared__ float vbuf[4][N][C];
    __shared__ float sgk[4][N];
    __shared__ float thb[4][N];

    const int wv = threadIdx.x >> 6;
    const int ln = threadIdx.x & 63;
    const int pid = blockIdx.x * 4 + wv;
    const int win = pid >> 3;
    const int Bi  = pid & 7;
    const int hw = win >> 5, ww = win & 31;
    const int b0 = ln >> 3, b1 = ln & 7;
    const size_t base = ((((size_t)Bi * 256) + (size_t)(hw * 8 + b0)) * 256
                         + (size_t)(ww * 8 + b1)) * C;

    float xr[C];
    {
        const float4* p = (const float4*)(x + base);
        #pragma unroll
        for (int i = 0; i < 7; ++i) {
            float4 t = p[i];
            xr[4*i+0] = t.x; xr[4*i+1] = t.y; xr[4*i+2] = t.z; xr[4*i+3] = t.w;
        }
    }
    float q[C];
    #pragma unroll
    for (int d = 0; d < C; ++d) {
        float a0 = 0.f, a1 = 0.f;
        #pragma unroll
        for (int c = 0; c < C; c += 2) {
            a0 += Wqk[d*C + c] * xr[c];
            a1 += Wqk[d*C + c + 1] * xr[c+1];
        }
        q[d] = a0 + a1;
    }
    float sq;
    {
        float a0 = 0.f, a1 = 0.f;
        #pragma unroll
        for (int d = 0; d < C; d += 2) { a0 += q[d]*Wpcq[d]; a1 += q[d+1]*Wpcq[d+1]; }
        sq = a0 + a1 + bpcq[0];
    }
    {
        float ak_sig = 0.f;
        #pragma unroll 1
        for (int d = 0; d < C; ++d) {
            float k0 = 0.f, k1 = 0.f, v0 = 0.f, v1 = 0.f;
            #pragma unroll
            for (int c = 0; c < C; c += 2) {
                k0 += Wqk[(C+d)*C + c] * xr[c];
                k1 += Wqk[(C+d)*C + c + 1] * xr[c+1];
                v0 += Wv[d*C + c] * xr[c];
                v1 += Wv[d*C + c + 1] * xr[c+1];
            }
            float kd = k0 + k1;
            kbuf[wv][ln][d] = kd;
            vbuf[wv][ln][d] = v0 + v1;
            ak_sig += kd * Wpck[d];
        }
        sgk[wv][ln] = ak_sig + bpck[0];
    }
    __syncthreads();

    float sim[N];
    float th = 0.f;
    float m = -1e30f;
    #pragma unroll
    for (int j = 0; j < N; ++j) {
        const float4* kj = (const float4*)(&kbuf[wv][j][0]);
        float a0 = 0.f, a1 = 0.f, a2 = 0.f, a3 = 0.f;
        #pragma unroll
        for (int c4 = 0; c4 < 7; ++c4) {
            float4 kk = kj[c4];
            a0 += q[4*c4+0] * kk.x;
            a1 += q[4*c4+1] * kk.y;
            a2 += q[4*c4+2] * kk.z;
            a3 += q[4*c4+3] * kk.w;
        }
        float sraw = (a0 + a1) + (a2 + a3);
        th += (j == ln) ? 0.f : sraw * Wm1[j];
        float ss = sraw * sq * sgk[wv][j];
        sim[j] = ss;
        m = fmaxf(m, ss);
    }
    thb[wv][ln] = th;
    __syncthreads();

    float tP;
    {
        const float* thw = &thb[wv][0];
        const float* wrow = Wm2a + ln * N;
        float a0 = 0.f, a1 = 0.f, a2 = 0.f, a3 = 0.f;
        #pragma unroll 4
        for (int i = 0; i < N; i += 4) {
            a0 += thw[i] * wrow[i];
            a1 += thw[i+1] * wrow[i+1];
            a2 += thw[i+2] * wrow[i+2];
            a3 += thw[i+3] * wrow[i+3];
        }
        float t = (a0 + a1) + (a2 + a3);
        t = (t >= 0.f) ? t : 0.1f * t;
        tP = t * Wm2b[ln];
    }
    float theta = tP;
    #pragma unroll
    for (int off = 32; off > 0; off >>= 1)
        theta += __shfl_xor(theta, off, 64);

    float o[C];
    #pragma unroll
    for (int d = 0; d < C; ++d) o[d] = 0.f;
    float Z = 0.f;
    #pragma unroll
    for (int j = 0; j < N; ++j) {
        float e = __expf(sim[j] - m);
        Z += e;
        float a = (sim[j] > theta) ? e : 0.f;
        const float4* vj = (const float4*)(&vbuf[wv][j][0]);
        #pragma unroll
        for (int c4 = 0; c4 < 7; ++c4) {
            float4 vvv = vj[c4];
            o[4*c4+0] += a * vvv.x;
            o[4*c4+1] += a * vvv.y;
            o[4*c4+2] += a * vvv.z;
            o[4*c4+3] += a * vvv.w;
        }
    }
    {
        float rz = 1.0f / Z;
        #pragma unroll
        for (int d = 0; d < C; ++d) o[d] *= rz;
    }
    float* yp = out + base;
    #pragma unroll 1
    for (int e = 0; e < C; ++e) {
        float a0 = 0.f, a1 = 0.f;
        #pragma unroll
        for (int d = 0; d < C; d += 2) {
            a0 += Wout[e*C + d] * o[d];
            a1 += Wout[e*C + d + 1] * o[d+1];
        }
        yp[e] = (a0 + a1) + bout[e];
    }
}

extern "C" void kernel_launch(void* const* d_in, const int* in_sizes, int n_in,
                              void* d_out, int out_size, void* d_ws, size_t ws_size,
                              hipStream_t stream) {
    const float* x     = (const float*)d_in[0];
    const float* W_qk  = (const float*)d_in[1];
    const float* W_v   = (const float*)d_in[2];
    const float* W_out = (const float*)d_in[3];
    const float* b_out = (const float*)d_in[4];
    const float* W_pcq = (const float*)d_in[5];
    const float* b_pcq = (const float*)d_in[6];
    const float* W_pck = (const float*)d_in[7];
    const float* b_pck = (const float*)d_in[8];
    const float* W_m1  = (const float*)d_in[9];
    const float* W_m2a = (const float*)d_in[10];
    const float* W_m2b = (const float*)d_in[11];
    float* y = (float*)d_out;

    const size_t need = (size_t)NPROB * PS * sizeof(float);  // ~172 MB
    if (ws_size >= need) {
        float* ws = (float*)d_ws;
        hipLaunchKernelGGL(proj_kernel, dim3(2048), dim3(256), 0, stream,
                           x, W_qk, W_v, W_pcq, b_pcq, W_pck, b_pck, ws);
        hipLaunchKernelGGL(attn_kernel, dim3(8192), dim3(64), 0, stream,
                           ws, W_out, b_out, W_m1, W_m2a, W_m2b, y);
    } else {
        hipLaunchKernelGGL(fa_fused_fb, dim3(2048), dim3(256), 0, stream,
                           x, W_qk, W_v, W_out, b_out, W_pcq, b_pcq,
                           W_pck, b_pck, W_m1, W_m2a, W_m2b, y);
    }
}

// Round 4
// 294.627 us; speedup vs baseline: 1.5848x; 1.5848x over previous
//
#include <hip/hip_runtime.h>
#include <math.h>

#define C 28   // channels == dim_head == rank
#define N 64   // tokens per window (8x8)

// LDS layout (float offsets). Region QT+KT+THP is overlaid by AT after sim
// is consumed; region V is overlaid by OT after AV consumes V.
#define QT_OFF   0      // [28][64]
#define KT_OFF   1792   // [28][64]
#define THP_OFF  3584   // [8][65] padded reduction scratch
#define AT_OFF   0      // [64][64] swizzled, overlays QT/KT/THP
#define V_OFF    4104   // [64][28]
#define OT_OFF   4104   // [64][28] overlays V
#define SQ_OFF   5896
#define SGK_OFF  5960
#define M_OFF    6024
#define Z_OFF    6088
#define TH_OFF   6152
#define LDS_FLOATS 6216  // 24864 B -> 6 blocks/CU

__global__ __launch_bounds__(64, 2)
void fa_tiled(const float* __restrict__ x,
              const float* __restrict__ Wqk,   // [56][28]
              const float* __restrict__ Wv,    // [28][28]
              const float* __restrict__ Wout,  // [28][28]
              const float* __restrict__ bout,  // [28]
              const float* __restrict__ Wpcq,  // [28]
              const float* __restrict__ bpcq,  // [1]
              const float* __restrict__ Wpck,  // [28]
              const float* __restrict__ bpck,  // [1]
              const float* __restrict__ Wm1,   // [64]
              const float* __restrict__ Wm2a,  // [64][64]
              const float* __restrict__ Wm2b,  // [64]
              float* __restrict__ out)
{
    __shared__ float S[LDS_FLOATS];

    const int ln  = threadIdx.x;       // 0..63
    const int pid = blockIdx.x;        // 0..8191, one wave per problem
    const int win = pid >> 3;
    const int Bi  = pid & 7;
    const int hw = win >> 5, ww = win & 31;
    const int b0 = ln >> 3, b1 = ln & 7;
    const size_t base = ((((size_t)Bi * 256) + (size_t)(hw * 8 + b0)) * 256
                         + (size_t)(ww * 8 + b1)) * C;

    const int ti = ln >> 3, tj = ln & 7;   // tile coords for GEMM phases

    // ================= Phase A: projections (lane = token) =================
    float xr[C];
    {
        const float4* p = (const float4*)(x + base);
        #pragma unroll
        for (int i = 0; i < 7; ++i) {
            float4 t = p[i];
            xr[4*i+0] = t.x; xr[4*i+1] = t.y; xr[4*i+2] = t.z; xr[4*i+3] = t.w;
        }
    }

    // q -> QT (transposed), sig_q (chains match R1)
    {
        float sqa0 = 0.f, sqa1 = 0.f;
        #pragma unroll 2
        for (int d4 = 0; d4 < 7; ++d4) {
            float qq[4];
            #pragma unroll
            for (int t = 0; t < 4; ++t) {
                const int d = 4*d4 + t;
                float a0 = 0.f, a1 = 0.f;
                #pragma unroll
                for (int c = 0; c < C; c += 2) {
                    a0 += Wqk[d*C + c]     * xr[c];
                    a1 += Wqk[d*C + c + 1] * xr[c+1];
                }
                qq[t] = a0 + a1;
                S[QT_OFF + d*64 + ln] = qq[t];
            }
            sqa0 += qq[0] * Wpcq[4*d4+0];
            sqa1 += qq[1] * Wpcq[4*d4+1];
            sqa0 += qq[2] * Wpcq[4*d4+2];
            sqa1 += qq[3] * Wpcq[4*d4+3];
        }
        S[SQ_OFF + ln] = sqa0 + sqa1 + bpcq[0];
    }

    // k -> KT (transposed), v -> V (row-major), sig_k (chains match R1)
    {
        float ak = 0.f;
        #pragma unroll 2
        for (int d4 = 0; d4 < 7; ++d4) {
            float kk[4], vv[4];
            #pragma unroll
            for (int t = 0; t < 4; ++t) {
                const int d = 4*d4 + t;
                float k0 = 0.f, k1 = 0.f, v0 = 0.f, v1 = 0.f;
                #pragma unroll
                for (int c = 0; c < C; c += 2) {
                    k0 += Wqk[(C+d)*C + c]     * xr[c];
                    k1 += Wqk[(C+d)*C + c + 1] * xr[c+1];
                    v0 += Wv[d*C + c]          * xr[c];
                    v1 += Wv[d*C + c + 1]      * xr[c+1];
                }
                kk[t] = k0 + k1;
                vv[t] = v0 + v1;
                S[KT_OFF + d*64 + ln] = kk[t];
            }
            ak += kk[0] * Wpck[4*d4+0];
            ak += kk[1] * Wpck[4*d4+1];
            ak += kk[2] * Wpck[4*d4+2];
            ak += kk[3] * Wpck[4*d4+3];
            *(float4*)&S[V_OFF + ln*C + 4*d4] = make_float4(vv[0], vv[1], vv[2], vv[3]);
        }
        S[SGK_OFF + ln] = ak + bpck[0];
    }
    __syncthreads();

    // ============ sim: 8x8 register tile per lane, lane=(ti,tj) ============
    float acc[8][8];   // acc[cc][rr] = sraw[8ti+rr][8tj+cc]
    #pragma unroll
    for (int cc = 0; cc < 8; ++cc)
        #pragma unroll
        for (int rr = 0; rr < 8; ++rr) acc[cc][rr] = 0.f;

    #pragma unroll 2
    for (int d = 0; d < C; ++d) {
        float4 qa = *(const float4*)&S[QT_OFF + d*64 + 8*ti];
        float4 qb = *(const float4*)&S[QT_OFF + d*64 + 8*ti + 4];
        float4 ka = *(const float4*)&S[KT_OFF + d*64 + 8*tj];
        float4 kb = *(const float4*)&S[KT_OFF + d*64 + 8*tj + 4];
        float q8[8] = {qa.x,qa.y,qa.z,qa.w,qb.x,qb.y,qb.z,qb.w};
        float k8[8] = {ka.x,ka.y,ka.z,ka.w,kb.x,kb.y,kb.z,kb.w};
        #pragma unroll
        for (int cc = 0; cc < 8; ++cc)
            #pragma unroll
            for (int rr = 0; rr < 8; ++rr)
                acc[cc][rr] += q8[rr] * k8[cc];
    }

    // ---- theta partials over this lane's j-range (diag excluded) ----
    {
        float4 wa = *(const float4*)&Wm1[8*tj];
        float4 wb = *(const float4*)&Wm1[8*tj + 4];
        float w8[8] = {wa.x,wa.y,wa.z,wa.w,wb.x,wb.y,wb.z,wb.w};
        #pragma unroll
        for (int rr = 0; rr < 8; ++rr) {
            float s = 0.f;
            #pragma unroll
            for (int cc = 0; cc < 8; ++cc) {
                float term = acc[cc][rr] * w8[cc];
                if (cc == rr) term = (ti == tj) ? 0.f : term;
                s += term;
            }
            S[THP_OFF + tj*65 + 8*ti + rr] = s;
        }
    }
    __syncthreads();
    {   // th[i]: reduce the 8 tj-partials (lane = i), ascending tj
        float th = 0.f;
        #pragma unroll
        for (int t = 0; t < 8; ++t) th += S[THP_OFF + t*65 + ln];
        S[TH_OFF + ln] = th;
    }
    __syncthreads();

    // ---- MLP2 (lane = i), then butterfly -> scalar theta in all lanes ----
    float theta;
    {
        const float* wrow = Wm2a + ln * N;
        float a0 = 0.f, a1 = 0.f, a2 = 0.f, a3 = 0.f;
        #pragma unroll 4
        for (int i4 = 0; i4 < 16; ++i4) {
            float4 t4 = *(const float4*)&S[TH_OFF + 4*i4];
            float4 w4 = *(const float4*)&wrow[4*i4];
            a0 += t4.x*w4.x; a1 += t4.y*w4.y; a2 += t4.z*w4.z; a3 += t4.w*w4.w;
        }
        float t = (a0 + a1) + (a2 + a3);
        t = (t >= 0.f) ? t : 0.1f * t;
        theta = t * Wm2b[ln];
        #pragma unroll
        for (int off = 32; off > 0; off >>= 1)
            theta += __shfl_xor(theta, off, 64);
    }

    // ---- Sigma scale (order matches R1: (sraw*sq)*sgk) ----
    float sq8[8], sg8[8], m8[8];
    {
        float4 a = *(const float4*)&S[SQ_OFF + 8*ti];
        float4 b = *(const float4*)&S[SQ_OFF + 8*ti + 4];
        sq8[0]=a.x; sq8[1]=a.y; sq8[2]=a.z; sq8[3]=a.w;
        sq8[4]=b.x; sq8[5]=b.y; sq8[6]=b.z; sq8[7]=b.w;
        float4 c = *(const float4*)&S[SGK_OFF + 8*tj];
        float4 d = *(const float4*)&S[SGK_OFF + 8*tj + 4];
        sg8[0]=c.x; sg8[1]=c.y; sg8[2]=c.z; sg8[3]=c.w;
        sg8[4]=d.x; sg8[5]=d.y; sg8[6]=d.z; sg8[7]=d.w;
    }
    #pragma unroll
    for (int cc = 0; cc < 8; ++cc)
        #pragma unroll
        for (int rr = 0; rr < 8; ++rr)
            acc[cc][rr] = (acc[cc][rr] * sq8[rr]) * sg8[cc];

    // ---- row max: local then cross-tj reduce ----
    #pragma unroll
    for (int rr = 0; rr < 8; ++rr) {
        float mp = -1e30f;
        #pragma unroll
        for (int cc = 0; cc < 8; ++cc) mp = fmaxf(mp, acc[cc][rr]);
        S[THP_OFF + tj*65 + 8*ti + rr] = mp;
    }
    __syncthreads();
    {
        float mv = -1e30f;
        #pragma unroll
        for (int t = 0; t < 8; ++t) mv = fmaxf(mv, S[THP_OFF + t*65 + ln]);
        S[M_OFF + ln] = mv;
    }
    __syncthreads();
    {
        float4 a = *(const float4*)&S[M_OFF + 8*ti];
        float4 b = *(const float4*)&S[M_OFF + 8*ti + 4];
        m8[0]=a.x; m8[1]=a.y; m8[2]=a.z; m8[3]=a.w;
        m8[4]=b.x; m8[5]=b.y; m8[6]=b.z; m8[7]=b.w;
    }

    // ---- exp, Z partial (unmasked), threshold mask in place ----
    #pragma unroll
    for (int rr = 0; rr < 8; ++rr) {
        float zp = 0.f;
        #pragma unroll
        for (int cc = 0; cc < 8; ++cc) {
            float ss = acc[cc][rr];
            float e = __expf(ss - m8[rr]);
            zp += e;
            acc[cc][rr] = (ss > theta) ? e : 0.f;
        }
        S[THP_OFF + tj*65 + 8*ti + rr] = zp;
    }
    __syncthreads();
    {   // Z[i]: ascending tj groups == ascending j (matches R1 association)
        float z = 0.f;
        #pragma unroll
        for (int t = 0; t < 8; ++t) z += S[THP_OFF + t*65 + ln];
        S[Z_OFF + ln] = z;
    }
    __syncthreads();

    // ---- write masked-e to AT (A^T layout, XOR-swizzled chunks) ----
    #pragma unroll
    for (int jj = 0; jj < 8; ++jj) {
        const int j  = 8*tj + jj;
        const int Kk = (tj + jj) & 7;
        const int c0 = 2*ti, c1 = 2*ti + 1;
        const int pc0 = (c0 & 8) | ((c0 + Kk) & 7);
        const int pc1 = (c1 & 8) | ((c1 + Kk) & 7);
        *(float4*)&S[AT_OFF + j*64 + pc0*4] = make_float4(acc[jj][0], acc[jj][1], acc[jj][2], acc[jj][3]);
        *(float4*)&S[AT_OFF + j*64 + pc1*4] = make_float4(acc[jj][4], acc[jj][5], acc[jj][6], acc[jj][7]);
    }
    __syncthreads();

    // ============ AV: lane=(ti,dg) computes out[8ti..+8][4dg..+4] ============
    const int dg  = tj;
    const int dgc = (dg < 7) ? dg : 6;   // dg==7 lanes duplicate dg==6, writes masked
    float av[8][4];
    #pragma unroll
    for (int rr = 0; rr < 8; ++rr)
        #pragma unroll
        for (int dc = 0; dc < 4; ++dc) av[rr][dc] = 0.f;

    #pragma unroll 2
    for (int j = 0; j < N; ++j) {
        const int Kk = (j + (j >> 3)) & 7;
        const int c0 = 2*ti, c1 = 2*ti + 1;
        const int pc0 = (c0 & 8) | ((c0 + Kk) & 7);
        const int pc1 = (c1 & 8) | ((c1 + Kk) & 7);
        float4 aa = *(const float4*)&S[AT_OFF + j*64 + pc0*4];
        float4 ab = *(const float4*)&S[AT_OFF + j*64 + pc1*4];
        float4 v4 = *(const float4*)&S[V_OFF + j*C + 4*dgc];
        float a8[8] = {aa.x,aa.y,aa.z,aa.w,ab.x,ab.y,ab.z,ab.w};
        #pragma unroll
        for (int rr = 0; rr < 8; ++rr) {
            av[rr][0] += a8[rr] * v4.x;
            av[rr][1] += a8[rr] * v4.y;
            av[rr][2] += a8[rr] * v4.z;
            av[rr][3] += a8[rr] * v4.w;
        }
    }
    {   // normalize by Z (1.0f/Z exact divide, matches R1)
        float4 a = *(const float4*)&S[Z_OFF + 8*ti];
        float4 b = *(const float4*)&S[Z_OFF + 8*ti + 4];
        float z8[8] = {a.x,a.y,a.z,a.w,b.x,b.y,b.z,b.w};
        #pragma unroll
        for (int rr = 0; rr < 8; ++rr) {
            float rz = 1.0f / z8[rr];
            av[rr][0] *= rz; av[rr][1] *= rz; av[rr][2] *= rz; av[rr][3] *= rz;
        }
    }
    __syncthreads();   // all V reads done before OT overlays V
    if (dg < 7) {
        #pragma unroll
        for (int rr = 0; rr < 8; ++rr)
            *(float4*)&S[OT_OFF + (8*ti+rr)*C + 4*dg] =
                make_float4(av[rr][0], av[rr][1], av[rr][2], av[rr][3]);
    }
    __syncthreads();

    // ============ epilogue: out projection (lane = token) ============
    float o[C];
    #pragma unroll
    for (int i = 0; i < 7; ++i) {
        float4 t = *(const float4*)&S[OT_OFF + ln*C + 4*i];
        o[4*i+0] = t.x; o[4*i+1] = t.y; o[4*i+2] = t.z; o[4*i+3] = t.w;
    }
    float y[C];
    #pragma unroll 2
    for (int e4 = 0; e4 < 7; ++e4) {
        #pragma unroll
        for (int t = 0; t < 4; ++t) {
            const int e = 4*e4 + t;
            float a0 = 0.f, a1 = 0.f;
            #pragma unroll
            for (int d = 0; d < C; d += 2) {
                a0 += Wout[e*C + d]     * o[d];
                a1 += Wout[e*C + d + 1] * o[d+1];
            }
            y[e] = (a0 + a1) + bout[e];
        }
    }
    {
        float4* yp = (float4*)(out + base);
        #pragma unroll
        for (int i = 0; i < 7; ++i)
            yp[i] = make_float4(y[4*i+0], y[4*i+1], y[4*i+2], y[4*i+3]);
    }
}

extern "C" void kernel_launch(void* const* d_in, const int* in_sizes, int n_in,
                              void* d_out, int out_size, void* d_ws, size_t ws_size,
                              hipStream_t stream) {
    const float* x     = (const float*)d_in[0];
    const float* W_qk  = (const float*)d_in[1];
    const float* W_v   = (const float*)d_in[2];
    const float* W_out = (const float*)d_in[3];
    const float* b_out = (const float*)d_in[4];
    const float* W_pcq = (const float*)d_in[5];
    const float* b_pcq = (const float*)d_in[6];
    const float* W_pck = (const float*)d_in[7];
    const float* b_pck = (const float*)d_in[8];
    const float* W_m1  = (const float*)d_in[9];
    const float* W_m2a = (const float*)d_in[10];
    const float* W_m2b = (const float*)d_in[11];
    float* y = (float*)d_out;

    // 8192 problems, one 64-thread wave per problem
    hipLaunchKernelGGL(fa_tiled, dim3(8192), dim3(64), 0, stream,
                       x, W_qk, W_v, W_out, b_out, W_pcq, b_pcq,
                       W_pck, b_pck, W_m1, W_m2a, W_m2b, y);
}